// Round 3
// baseline (5881.293 us; speedup 1.0000x reference)
//
#include <hip/hip_runtime.h>

typedef short short8 __attribute__((ext_vector_type(8)));
typedef short short4v __attribute__((ext_vector_type(4)));
typedef float f32x4 __attribute__((ext_vector_type(4)));

#define DD 4096
#define BN 64        // n-cols per block (256B fp32 per k-row -> DRAM-page friendly)
#define KSPLIT 8     // matches 8 XCDs; ks = bid&7 -> per-XCD A-slab L2 residency
#define KSPAN 512
#define KT 64
#define NITER 8      // KSPAN/KT
#define WP 72        // padded k-extent (bf16 elems) of LDS W tile (144B rows)
#define NLAYER 15
#define NSTRIP 64    // DD/BN

__device__ __forceinline__ unsigned short f2bf(float f) {
  unsigned u = __float_as_uint(f);
  u += 0x7FFFu + ((u >> 16) & 1u);   // round-to-nearest-even
  return (unsigned short)(u >> 16);
}

// fp32 x -> bf16 h in BLOCKED layout [n>>6][m][n&63]; also zero split-K counters
__global__ __launch_bounds__(256) void k_tobf16(const float* __restrict__ x,
                                                unsigned short* __restrict__ h,
                                                int* __restrict__ cnt) {
  const int gid = blockIdx.x * 256 + threadIdx.x;
  if (gid < NLAYER * NSTRIP) cnt[gid] = 0;
  const size_t e = (size_t)gid * 8;
  f32x4 a = *(const f32x4*)(x + e);
  f32x4 b = *(const f32x4*)(x + e + 4);
  short8 v;
#pragma unroll
  for (int j = 0; j < 4; ++j) { v[j] = (short)f2bf(a[j]); v[4 + j] = (short)f2bf(b[j]); }
  const int m = (int)(e >> 12), n = (int)(e & (DD - 1));
  *(short8*)(h + (size_t)(n >> 6) * 16384 + m * 64 + (n & 63)) = v;
}

// quad transpose (4k x 4n -> 4n x 4k) + swizzled LDS write of 4 bf16 (one n, 4 k)
__device__ __forceinline__ void xw(unsigned short (*lds)[WP], f32x4 v, int K0, int lane) {
  unsigned d0 = (unsigned)f2bf(v[0]) | ((unsigned)f2bf(v[1]) << 16);
  unsigned d1 = (unsigned)f2bf(v[2]) | ((unsigned)f2bf(v[3]) << 16);
  const int p = lane >> 4;
  unsigned o0 = (unsigned)__shfl_xor((int)d0, 16);
  unsigned o1 = (unsigned)__shfl_xor((int)d1, 16);
  unsigned r0, r1;
  if ((p & 1) == 0) { r0 = (d0 & 0xFFFFu) | (o0 << 16); r1 = (d0 >> 16) | (o0 & 0xFFFF0000u); }
  else              { r0 = (o1 & 0xFFFFu) | (d1 << 16); r1 = (o1 >> 16) | (d1 & 0xFFFF0000u); }
  unsigned q0 = (unsigned)__shfl_xor((int)r0, 32);
  unsigned q1 = (unsigned)__shfl_xor((int)r1, 32);
  unsigned lo, hi;
  if (p < 2) { lo = r0; hi = q0; } else { lo = q1; hi = r1; }
  const int nw = 4 * (lane & 15) + (((p & 1) << 1) | (p >> 1));
  const int kc = K0 ^ ((nw & 7) << 3);
  unsigned* dst = (unsigned*)&lds[nw][kc];
  dst[0] = lo; dst[1] = hi;
}

// Split-K GEMM, fused last-block reduction (+bias+relu+bf16 h / fp32 out).
// Block (strip, ks): partial [256 x 64] over K range [ks*512, +512).
__global__ __launch_bounds__(512, 4) void k_gemm(const unsigned short* __restrict__ A,
                                                 const float* __restrict__ W,
                                                 const float* __restrict__ bias,
                                                 float* __restrict__ part,
                                                 int* __restrict__ cnt,
                                                 unsigned short* __restrict__ hout,
                                                 float* __restrict__ fout) {
  __shared__ __align__(16) unsigned short wlds[2][BN][WP];
  __shared__ int isLast;
  const int bid   = blockIdx.x;
  const int ks    = bid & (KSPLIT - 1);  // == XCD id under round-robin dispatch
  const int strip = bid >> 3;
  const int kbeg  = ks * KSPAN;
  const int tid   = threadIdx.x;
  const int lane  = tid & 63;
  const int wave  = tid >> 6;
  const int p     = lane >> 4;

  // W stage source: contiguous f32x4, 256B per k-row per 16 lanes
  const float* wsrc = W + (size_t)(kbeg + 4 * wave + p) * DD + strip * 64 + 4 * (lane & 15);

  const int wm = wave >> 2, wn = wave & 3;
  const int mb = wm * 128;
  const int ncol = wn * 16 + (lane & 15);   // tile-local output col 0..63
  const int swz  = (ncol & 7) << 3;

  const f32x4 fz = {0.f, 0.f, 0.f, 0.f};
  f32x4 acc[8];
#pragma unroll
  for (int i = 0; i < 8; ++i) acc[i] = fz;

  // prologue: stage W tile 0 -> buf 0
  {
    f32x4 v0 = *(const f32x4*)wsrc;
    f32x4 v1 = *(const f32x4*)(wsrc + (size_t)32 * DD);
    xw(wlds[0], v0, 4 * wave, lane);
    xw(wlds[0], v1, 4 * wave + 32, lane);
  }
  __syncthreads();

  for (int it = 0; it < NITER; ++it) {
    f32x4 v0, v1;
    if (it + 1 < NITER) {               // issue next W loads early (hide HBM latency)
      const float* s = wsrc + (size_t)(it + 1) * KT * DD;
      v0 = *(const f32x4*)s;
      v1 = *(const f32x4*)(s + (size_t)32 * DD);
    }
    const int buf = it & 1;
#pragma unroll
    for (int kk = 0; kk < 2; ++kk) {
      short8 bfr = *(const short8*)(&wlds[buf][ncol][(kk * 32 + 8 * p) ^ swz]);
      const unsigned short* abase = A + (size_t)(ks * 8 + it) * 16384 + kk * 32 + 8 * p;
#pragma unroll
      for (int mf = 0; mf < 8; ++mf) {
        short8 af = *(const short8*)(abase + (size_t)(mb + mf * 16 + (lane & 15)) * 64);
        acc[mf] = __builtin_amdgcn_mfma_f32_16x16x32_bf16(af, bfr, acc[mf], 0, 0, 0);
      }
    }
    if (it + 1 < NITER) {
      xw(wlds[buf ^ 1], v0, 4 * wave, lane);
      xw(wlds[buf ^ 1], v1, 4 * wave + 32, lane);
    }
    __syncthreads();
  }

  // store fp32 partial tile (blocked [256][64], fully dense per block)
  float* pdst = part + (size_t)ks * (NSTRIP * 16384) + (size_t)strip * 16384;
#pragma unroll
  for (int mf = 0; mf < 8; ++mf)
#pragma unroll
    for (int j = 0; j < 4; ++j)
      pdst[(size_t)(mb + mf * 16 + 4 * p + j) * 64 + ncol] = acc[mf][j];

  __threadfence();          // release: flush partial stores (cross-XCD visibility)
  __syncthreads();
  if (tid == 0) isLast = (atomicAdd(&cnt[strip], 1) == KSPLIT - 1);
  __syncthreads();
  if (!isLast) return;
  __threadfence();          // acquire: invalidate stale lines before reading peers

  const float* pb = part + (size_t)strip * 16384;
#pragma unroll
  for (int c = 0; c < 8; ++c) {
    const int i = tid * 32 + c * 4;
    f32x4 s = *(const f32x4*)(pb + i);
#pragma unroll
    for (int q = 1; q < KSPLIT; ++q)
      s += *(const f32x4*)(pb + (size_t)q * (NSTRIP * 16384) + i);
    s += *(const f32x4*)(bias + strip * 64 + (i & 63));
#pragma unroll
    for (int j = 0; j < 4; ++j) s[j] = fmaxf(s[j], 0.f);
    short4v v;
#pragma unroll
    for (int j = 0; j < 4; ++j) v[j] = (short)f2bf(s[j]);
    *(short4v*)(hout + (size_t)strip * 16384 + i) = v;   // blocked bf16
    if (fout) *(f32x4*)(fout + (size_t)(i >> 6) * DD + strip * 64 + (i & 63)) = s;
  }
}

extern "C" void kernel_launch(void* const* d_in, const int* in_sizes, int n_in,
                              void* d_out, int out_size, void* d_ws, size_t ws_size,
                              hipStream_t stream) {
  const float* x = (const float*)d_in[0];
  const float* W = (const float*)d_in[1];
  const float* b = (const float*)d_in[2];
  float* out = (float*)d_out;

  char* ws = (char*)d_ws;
  unsigned short* h0 = (unsigned short*)ws;                    // 2 MB bf16 (blocked)
  unsigned short* h1 = (unsigned short*)(ws + (1 << 21));      // 2 MB
  float* part = (float*)(ws + (1 << 22));                      // 8 x 4 MB fp32 partials
  int* cnt = (int*)(ws + (1 << 22) + (32 << 20));              // 15*64 counters

  k_tobf16<<<512, 256, 0, stream>>>(x, h0, cnt);
  unsigned short* hc = h0;
  unsigned short* hn = h1;
  for (int l = 0; l < NLAYER; ++l) {
    k_gemm<<<512, 512, 0, stream>>>(hc, W + (size_t)l * DD * DD, b + (size_t)l * DD,
                                    part, cnt + l * NSTRIP, hn,
                                    (l == NLAYER - 1) ? out : nullptr);
    unsigned short* t = hc; hc = hn; hn = t;
  }
}

// Round 4
// 1773.214 us; speedup vs baseline: 3.3167x; 3.3167x over previous
//
#include <hip/hip_runtime.h>

typedef short short8 __attribute__((ext_vector_type(8)));
typedef float f32x4 __attribute__((ext_vector_type(4)));

#define DD 4096
#define BN 64        // n-cols per block: 256B of W per k-row -> DRAM-page friendly
#define KT 128       // k per LDS tile
#define NIT 32       // DD/KT full-K per block (no split-K, no fences, no partials)
#define WP 136       // padded k-extent (bf16) of LDS tile: 272B rows
#define NLAYER 15

__device__ __forceinline__ unsigned short f2bf(float f) {
  unsigned u = __float_as_uint(f);
  u += 0x7FFFu + ((u >> 16) & 1u);   // round-to-nearest-even
  return (unsigned short)(u >> 16);
}

// fp32 x -> bf16 h in BLOCKED layout [k>>6][m][k&63] (what k_gemm's A-path reads)
__global__ __launch_bounds__(256) void k_tobf16(const float* __restrict__ x,
                                                unsigned short* __restrict__ h) {
  const size_t e = ((size_t)blockIdx.x * 256 + threadIdx.x) * 8;
  f32x4 a = *(const f32x4*)(x + e);
  f32x4 b = *(const f32x4*)(x + e + 4);
  short8 v;
#pragma unroll
  for (int j = 0; j < 4; ++j) { v[j] = (short)f2bf(a[j]); v[4 + j] = (short)f2bf(b[j]); }
  const int m = (int)(e >> 12), n = (int)(e & (DD - 1));
  *(short8*)(h + (size_t)(n >> 6) * 16384 + m * 64 + (n & 63)) = v;
}

// quad transpose (4k x 4n -> 4n x 4k) + swizzled LDS write of 4 bf16 (one n, 4 k)
// (verified correct in R3: absmax matched the non-transposed path)
__device__ __forceinline__ void xw(unsigned short (*lds)[WP], f32x4 v, int K0, int lane) {
  unsigned d0 = (unsigned)f2bf(v[0]) | ((unsigned)f2bf(v[1]) << 16);
  unsigned d1 = (unsigned)f2bf(v[2]) | ((unsigned)f2bf(v[3]) << 16);
  const int p = lane >> 4;
  unsigned o0 = (unsigned)__shfl_xor((int)d0, 16);
  unsigned o1 = (unsigned)__shfl_xor((int)d1, 16);
  unsigned r0, r1;
  if ((p & 1) == 0) { r0 = (d0 & 0xFFFFu) | (o0 << 16); r1 = (d0 >> 16) | (o0 & 0xFFFF0000u); }
  else              { r0 = (o1 & 0xFFFFu) | (d1 << 16); r1 = (o1 >> 16) | (d1 & 0xFFFF0000u); }
  unsigned q0 = (unsigned)__shfl_xor((int)r0, 32);
  unsigned q1 = (unsigned)__shfl_xor((int)r1, 32);
  unsigned lo, hi;
  if (p < 2) { lo = r0; hi = q0; } else { lo = q1; hi = r1; }
  const int nw = 4 * (lane & 15) + (((p & 1) << 1) | (p >> 1));
  const int kc = K0 ^ ((nw & 7) << 3);
  unsigned* dst = (unsigned*)&lds[nw][kc];
  dst[0] = lo; dst[1] = hi;
}

// Full-K GEMM with fused bias+relu+bf16 (or fp32 final) epilogue.
// Block = one 256x64 output strip; 16 waves x 16 rows; K=4096 in 32 tiles of 128.
// W: reg-prefetch depth 2 -> shuffle-transposed, XOR-swizzled LDS double buffer.
// A: bf16 blocked [k>>6][256][64], read direct from global (L2-resident per XCD).
__global__ __launch_bounds__(1024, 4) void k_gemm(const unsigned short* __restrict__ A,
                                                  const float* __restrict__ W,
                                                  const float* __restrict__ bias,
                                                  unsigned short* __restrict__ hout,
                                                  float* __restrict__ fout) {
  __shared__ __align__(16) unsigned short wlds[2][BN][WP];
  const int bid  = blockIdx.x;
  const int n0   = bid * BN;
  const int tid  = threadIdx.x;
  const int lane = tid & 63;
  const int wave = tid >> 6;          // 0..15
  const int p    = lane >> 4;         // 0..3

  // W stage source: k-row 4*wave+p, 16 consecutive f32x4 lanes -> 256B per k-row
  const float* wsrc = W + (size_t)(4 * wave + p) * DD + n0 + 4 * (lane & 15);
  const unsigned short* abase = A + (size_t)(wave * 16 + (lane & 15)) * 64 + 8 * p;

  const f32x4 fz = {0.f, 0.f, 0.f, 0.f};
  f32x4 acc[4];
#pragma unroll
  for (int i = 0; i < 4; ++i) acc[i] = fz;

  // reg prefetch buffers: reg{0,1}{a,b} hold one 128x64 W tile each (a: rows+0, b: rows+64)
  f32x4 r0a, r0b, r1a, r1b;
  {
    f32x4 ta = *(const f32x4*)wsrc;
    f32x4 tb = *(const f32x4*)(wsrc + (size_t)64 * DD);
    r1a = *(const f32x4*)(wsrc + (size_t)1 * KT * DD);
    r1b = *(const f32x4*)(wsrc + (size_t)1 * KT * DD + (size_t)64 * DD);
    xw(wlds[0], ta, 4 * wave, lane);
    xw(wlds[0], tb, 4 * wave + 64, lane);
    r0a = *(const f32x4*)(wsrc + (size_t)2 * KT * DD);
    r0b = *(const f32x4*)(wsrc + (size_t)2 * KT * DD + (size_t)64 * DD);
  }
  __syncthreads();

  const int swz = ((lane & 7) << 3);  // read-side XOR for col n: n&7 == lane&7

#define GEMM_ITER(IT, RA, RB)                                                   \
  do {                                                                          \
    const int buf = (IT) & 1;                                                   \
    _Pragma("unroll")                                                           \
    for (int kk = 0; kk < 4; ++kk) {                                            \
      short8 af = *(const short8*)(abase + (size_t)((IT) * 2 + (kk >> 1)) * 16384 \
                                   + (kk & 1) * 32);                            \
      _Pragma("unroll")                                                         \
      for (int nf = 0; nf < 4; ++nf) {                                          \
        short8 bfr = *(const short8*)(&wlds[buf][nf * 16 + (lane & 15)]         \
                                      [(kk * 32 + 8 * p) ^ swz]);               \
        acc[nf] = __builtin_amdgcn_mfma_f32_16x16x32_bf16(af, bfr, acc[nf], 0, 0, 0); \
      }                                                                         \
    }                                                                           \
    __syncthreads();                                                            \
    if ((IT) + 1 < NIT) {                                                       \
      xw(wlds[buf ^ 1], RA, 4 * wave, lane);                                    \
      xw(wlds[buf ^ 1], RB, 4 * wave + 64, lane);                               \
    }                                                                           \
    if ((IT) + 3 < NIT) {                                                       \
      const float* s = wsrc + (size_t)((IT) + 3) * KT * DD;                     \
      RA = *(const f32x4*)s;                                                    \
      RB = *(const f32x4*)(s + (size_t)64 * DD);                                \
    }                                                                           \
    __syncthreads();                                                            \
  } while (0)

  for (int it = 0; it < NIT; it += 2) {
    GEMM_ITER(it, r1a, r1b);          // even it: writes tile it+1 (reg1), reissues reg1
    GEMM_ITER(it + 1, r0a, r0b);      // odd it: reg0
  }
#undef GEMM_ITER

  // fused epilogue: bias + relu; bf16 blocked hout, or fp32 [m][n] on last layer
  const int nb = lane & 15;
#pragma unroll
  for (int nf = 0; nf < 4; ++nf) {
    const float bv = bias[n0 + nf * 16 + nb];
#pragma unroll
    for (int j = 0; j < 4; ++j) {
      float s = acc[nf][j] + bv;
      s = fmaxf(s, 0.f);
      const int row = wave * 16 + 4 * p + j;
      if (fout) fout[(size_t)row * DD + n0 + nf * 16 + nb] = s;
      else hout[(size_t)bid * 16384 + row * 64 + nf * 16 + nb] = f2bf(s);
    }
  }
}

extern "C" void kernel_launch(void* const* d_in, const int* in_sizes, int n_in,
                              void* d_out, int out_size, void* d_ws, size_t ws_size,
                              hipStream_t stream) {
  const float* x = (const float*)d_in[0];
  const float* W = (const float*)d_in[1];
  const float* b = (const float*)d_in[2];
  float* out = (float*)d_out;

  char* ws = (char*)d_ws;
  unsigned short* h0 = (unsigned short*)ws;               // 2 MB bf16 (blocked)
  unsigned short* h1 = (unsigned short*)(ws + (1 << 21)); // 2 MB

  k_tobf16<<<512, 256, 0, stream>>>(x, h0);
  unsigned short* hc = h0;
  unsigned short* hn = h1;
  for (int l = 0; l < NLAYER; ++l) {
    const bool last = (l == NLAYER - 1);
    k_gemm<<<64, 1024, 0, stream>>>(hc, W + (size_t)l * DD * DD, b + (size_t)l * DD,
                                    hn, last ? out : nullptr);
    unsigned short* t = hc; hc = hn; hn = t;
  }
}

// Round 5
// 686.471 us; speedup vs baseline: 8.5674x; 2.5831x over previous
//
#include <hip/hip_runtime.h>

typedef short short8 __attribute__((ext_vector_type(8)));
typedef float f32x4 __attribute__((ext_vector_type(4)));

#define DD 4096
#define BM 128       // m rows per block
#define BN 32        // n cols per block
#define KT 128       // k per LDS tile
#define NIT 32       // DD/KT
#define WD 6         // W register-pipeline depth (issue tile t+5 at iter t)
#define NLAYER 15

__device__ __forceinline__ unsigned short f2bf(float f) {
  unsigned u = __float_as_uint(f);
  u += 0x7FFFu + ((u >> 16) & 1u);   // round-to-nearest-even
  return (unsigned short)(u >> 16);
}

// fp32 x [256][4096] -> bf16 h in blocked layout [kb=k>>5][m 256][k&31]
__global__ __launch_bounds__(256) void k_tobf16(const float* __restrict__ x,
                                                unsigned short* __restrict__ h) {
  const size_t e = ((size_t)blockIdx.x * 256 + threadIdx.x) * 8;
  const int m = (int)(e >> 12), n = (int)(e & (DD - 1));
  f32x4 a = *(const f32x4*)(x + e);
  f32x4 b = *(const f32x4*)(x + e + 4);
  short8 v;
#pragma unroll
  for (int j = 0; j < 4; ++j) { v[j] = (short)f2bf(a[j]); v[4 + j] = (short)f2bf(b[j]); }
  *(short8*)(h + (size_t)(n >> 5) * 8192 + m * 32 + (n & 31)) = v;
}

// One full layer: C[256,4096] = relu(A @ W + b). Block = [128m x 32n], full K.
// W fp32 k-major per thread (8 stride-16KB dwords), depth-WD register pipeline,
// converted bf16 into XOR-swizzled LDS double buffer (no transpose needed).
// A bf16 blocked [k>>5][256][32] -> fragment loads are 16B coalesced, L2-resident.
__global__ __launch_bounds__(512, 2) void k_gemm(const unsigned short* __restrict__ A,
                                                 const float* __restrict__ W,
                                                 const float* __restrict__ bias,
                                                 unsigned short* __restrict__ hout,
                                                 float* __restrict__ fout) {
  __shared__ __align__(16) unsigned char smem[17408];
  unsigned short* wlds = (unsigned short*)smem;      // [2][32 cols][128 k] bf16 = 16 KB
  float (*clds)[33] = (float (*)[33])smem;           // [128][33] f32 = 16.9 KB (epilogue)

  const int bid   = blockIdx.x;
  const int strip = bid & 127;          // n-strip; same strip pair (bid, bid+128) -> same XCD
  const int mt    = bid >> 7;           // 0..1 m-tile
  const int n0    = strip * BN;
  const int tid   = threadIdx.x;
  const int lane  = tid & 63;
  const int wave  = tid >> 6;           // 0..7
  const int l15   = lane & 15;
  const int p     = lane >> 4;          // 0..3

  // ---- W staging role: col sn, k-chunk kg (8 consecutive k-rows) ----
  const int sn = tid & 31, kg = tid >> 5;                 // kg 0..15
  const float* wsrc = W + (size_t)(kg * 8) * DD + n0 + sn;
  const int wofs = sn * KT + 8 * (kg ^ (sn & 15));        // swizzled elem offset in buffer

  // ---- compute roles ----
  const int mq    = wave & 3;           // m-quarter (32 rows)
  const int nh    = wave >> 2;          // n-half (16 cols)
  const int grow0 = mt * BM + mq * 32 + l15;              // + mf*16 -> global A row
  const int ncol  = nh * 16 + l15;                        // tile-local output col
  const unsigned short* Ab = A + (size_t)grow0 * 32 + 8 * p;

  const f32x4 fz = {0.f, 0.f, 0.f, 0.f};
  f32x4 acc[2];
  acc[0] = fz; acc[1] = fz;

  float  wbuf[WD][8];
  short8 abuf[2][8];

  // ---- prologue: issue W tiles 0..WD-2, A tile 0; stage tile 0 -> LDS[0] ----
#pragma unroll
  for (int t = 0; t < WD - 1; ++t)
#pragma unroll
    for (int j = 0; j < 8; ++j)
      wbuf[t][j] = wsrc[((size_t)t * KT + j) * DD];
#pragma unroll
  for (int mf = 0; mf < 2; ++mf)
#pragma unroll
    for (int kk = 0; kk < 4; ++kk)
      abuf[0][mf * 4 + kk] = *(const short8*)(Ab + ((size_t)kk * 256 + mf * 16) * 32);
  {
    short8 v;
#pragma unroll
    for (int j = 0; j < 8; ++j) v[j] = (short)f2bf(wbuf[0][j]);
    *(short8*)(wlds + wofs) = v;
  }
  __syncthreads();

  // ---- main loop: one barrier per iter; W consumed WD-1 iters after issue ----
#pragma unroll
  for (int it = 0; it < NIT; ++it) {
    const int cbuf = it & 1;
    if (it + WD - 1 < NIT) {                       // issue W tile it+WD-1
      const int t = it + WD - 1, s = t % WD;
#pragma unroll
      for (int j = 0; j < 8; ++j)
        wbuf[s][j] = wsrc[((size_t)t * KT + j) * DD];
    }
    if (it + 1 < NIT) {                            // issue A tile it+1
#pragma unroll
      for (int mf = 0; mf < 2; ++mf)
#pragma unroll
        for (int kk = 0; kk < 4; ++kk)
          abuf[(it + 1) & 1][mf * 4 + kk] =
              *(const short8*)(Ab + ((size_t)((it + 1) * 4 + kk) * 256 + mf * 16) * 32);
    }
    if (it + 1 < NIT) {                            // stage tile it+1 (loads long complete)
      const int s = (it + 1) % WD;
      short8 v;
#pragma unroll
      for (int j = 0; j < 8; ++j) v[j] = (short)f2bf(wbuf[s][j]);
      *(short8*)(wlds + (cbuf ^ 1) * 4096 + wofs) = v;
    }
#pragma unroll
    for (int kk = 0; kk < 4; ++kk) {               // compute tile it
      short8 bf = *(const short8*)(wlds + cbuf * 4096 + ncol * KT +
                                   8 * ((4 * kk + p) ^ (ncol & 15)));
#pragma unroll
      for (int mf = 0; mf < 2; ++mf)
        acc[mf] = __builtin_amdgcn_mfma_f32_16x16x32_bf16(abuf[it & 1][mf * 4 + kk], bf,
                                                          acc[mf], 0, 0, 0);
    }
    __syncthreads();
  }

  // ---- epilogue: bounce acc through LDS for coalesced writes ----
#pragma unroll
  for (int mf = 0; mf < 2; ++mf)
#pragma unroll
    for (int j = 0; j < 4; ++j)
      clds[mq * 32 + mf * 16 + 4 * p + j][ncol] = acc[mf][j];
  __syncthreads();

  const int row = tid >> 2;             // 0..127 (block-local)
  const int nb  = (tid & 3) * 8;        // 0,8,16,24
  float v[8];
#pragma unroll
  for (int j = 0; j < 8; ++j)
    v[j] = fmaxf(clds[row][nb + j] + bias[n0 + nb + j], 0.f);

  if (fout) {
    f32x4 o0, o1;
#pragma unroll
    for (int j = 0; j < 4; ++j) { o0[j] = v[j]; o1[j] = v[4 + j]; }
    float* dst = fout + (size_t)(mt * BM + row) * DD + n0 + nb;
    *(f32x4*)dst = o0;
    *(f32x4*)(dst + 4) = o1;
  } else {
    short8 o;
#pragma unroll
    for (int j = 0; j < 8; ++j) o[j] = (short)f2bf(v[j]);
    *(short8*)(hout + (size_t)strip * 8192 + (mt * BM + row) * 32 + nb) = o;
  }
}

extern "C" void kernel_launch(void* const* d_in, const int* in_sizes, int n_in,
                              void* d_out, int out_size, void* d_ws, size_t ws_size,
                              hipStream_t stream) {
  const float* x = (const float*)d_in[0];
  const float* W = (const float*)d_in[1];
  const float* b = (const float*)d_in[2];
  float* out = (float*)d_out;

  char* ws = (char*)d_ws;
  unsigned short* h0 = (unsigned short*)ws;               // 2 MB bf16 (blocked)
  unsigned short* h1 = (unsigned short*)(ws + (1 << 21)); // 2 MB

  k_tobf16<<<512, 256, 0, stream>>>(x, h0);
  unsigned short* hc = h0;
  unsigned short* hn = h1;
  for (int l = 0; l < NLAYER; ++l) {
    const bool last = (l == NLAYER - 1);
    k_gemm<<<256, 512, 0, stream>>>(hc, W + (size_t)l * DD * DD, b + (size_t)l * DD,
                                    hn, last ? out : nullptr);
    unsigned short* t = hc; hc = hn; hn = t;
  }
}

// Round 6
// 509.254 us; speedup vs baseline: 11.5488x; 1.3480x over previous
//
#include <hip/hip_runtime.h>

typedef short short8 __attribute__((ext_vector_type(8)));
typedef float f32x4 __attribute__((ext_vector_type(4)));
typedef unsigned u32x4 __attribute__((ext_vector_type(4)));

#define DD 4096
#define KSL 16        // split-K factor; ks = bid&15, ks&7 == XCD under round-robin
#define KSLAB 256     // DD/KSL k-rows per block
#define NT 8          // k-tiles of 32 per block
#define NLAYER 15

__device__ __forceinline__ unsigned short f2bf(float f) {
  unsigned u = __float_as_uint(f);
  u += 0x7FFFu + ((u >> 16) & 1u);   // round-to-nearest-even
  return (unsigned short)(u >> 16);
}
__device__ __forceinline__ float bf2f(unsigned short b) {
  return __uint_as_float(((unsigned)b) << 16);
}

// fp32 x [256][4096] -> bf16 h blocked [k>>5][m 256][k&31]
__global__ __launch_bounds__(256) void k_tobf16(const float* __restrict__ x,
                                                unsigned short* __restrict__ h) {
  const size_t e = ((size_t)blockIdx.x * 256 + threadIdx.x) * 8;
  const int m = (int)(e >> 12), n = (int)(e & (DD - 1));
  f32x4 a = *(const f32x4*)(x + e);
  f32x4 b = *(const f32x4*)(x + e + 4);
  short8 v;
#pragma unroll
  for (int j = 0; j < 4; ++j) { v[j] = (short)f2bf(a[j]); v[4 + j] = (short)f2bf(b[j]); }
  *(short8*)(h + (size_t)(n >> 5) * 8192 + m * 32 + (n & 31)) = v;
}

// 4x4 quad transpose across p-lane groups (verified R3/R4): input v = 4 consecutive
// n-cols at k-row (base+p); output: lane nw holds (1 n-col, 4 k) packed in lo/hi.
__device__ __forceinline__ void qtrans(f32x4 v, int p, unsigned& lo, unsigned& hi) {
  unsigned d0 = (unsigned)f2bf(v[0]) | ((unsigned)f2bf(v[1]) << 16);
  unsigned d1 = (unsigned)f2bf(v[2]) | ((unsigned)f2bf(v[3]) << 16);
  unsigned o0 = (unsigned)__shfl_xor((int)d0, 16);
  unsigned o1 = (unsigned)__shfl_xor((int)d1, 16);
  unsigned r0, r1;
  if ((p & 1) == 0) { r0 = (d0 & 0xFFFFu) | (o0 << 16); r1 = (d0 >> 16) | (o0 & 0xFFFF0000u); }
  else              { r0 = (o1 & 0xFFFFu) | (d1 << 16); r1 = (o1 >> 16) | (d1 & 0xFFFF0000u); }
  unsigned q0 = (unsigned)__shfl_xor((int)r0, 32);
  unsigned q1 = (unsigned)__shfl_xor((int)r1, 32);
  if (p < 2) { lo = r0; hi = q0; } else { lo = q1; hi = r1; }
}

// Split-K GEMM partial: block (nblk, ks) computes bf16 partial [256 m x 256 n] over
// k in [ks*256, +256). W read as 1KB-contiguous chunks per k-row (f32x4 lanes),
// transposed in-register into fragment-blocked LDS [kg][n][8k] (seq. ds_read_b128).
// A bf16 blocked, L2-resident per XCD (same-ks blocks share the 128KB A-slab).
__global__ __launch_bounds__(512, 2) void k_gemm(const unsigned short* __restrict__ A,
                                                 const float* __restrict__ W,
                                                 unsigned short* __restrict__ part) {
  __shared__ __align__(16) unsigned char smem[32768];  // 2 x 16KB W-frag buffers
  const int bid  = blockIdx.x;
  const int ks   = bid & (KSL - 1);
  const int nblk = bid >> 4;
  const int n0   = nblk * 256;
  const int tid  = threadIdx.x;
  const int lane = tid & 63;
  const int wave = tid >> 6;        // 0..7
  const int l15  = lane & 15;
  const int p    = lane >> 4;       // 0..3
  const int pp   = ((p & 1) << 1) | (p >> 1);
  const int nw   = 4 * l15 + pp;    // transposed n-col within 64-strip

  // two staging assignments per wave: q in {wave, wave+8}; kg=q&3 (8-k group), ns=q>>2
  const int kg0 = wave & 3, ns0 = wave >> 2;        // q = wave   -> ns 0..1
  const int kg1 = kg0,      ns1 = ns0 + 2;          // q = wave+8 -> ns 2..3
  const float* w0 = W + (size_t)(ks * KSLAB + 8 * kg0 + p) * DD + n0 + ns0 * 64 + 4 * l15;
  const float* w1 = W + (size_t)(ks * KSLAB + 8 * kg1 + p) * DD + n0 + ns1 * 64 + 4 * l15;

  const int wm = wave & 3, wn = wave >> 2;          // wave tile [64 m x 128 n]
  const size_t arow = (size_t)(wm * 64 + l15) * 32 + 8 * p;   // + mf*16*32
  const unsigned short* Ab = A + (size_t)ks * 8 * 8192 + arow;

  const f32x4 fz = {0.f, 0.f, 0.f, 0.f};
  f32x4 acc[4][8];
#pragma unroll
  for (int i = 0; i < 4; ++i)
#pragma unroll
    for (int j = 0; j < 8; ++j) acc[i][j] = fz;

  f32x4 wr[2][4];        // [slot][va0,vb0,va1,vb1]
  short8 ar[2][4];

#define LOADW(T, S)                                                   \
  do {                                                                \
    const float* s0_ = w0 + (size_t)(T) * 32 * DD;                    \
    const float* s1_ = w1 + (size_t)(T) * 32 * DD;                    \
    wr[S][0] = *(const f32x4*)s0_;                                    \
    wr[S][1] = *(const f32x4*)(s0_ + 4 * DD);                         \
    wr[S][2] = *(const f32x4*)s1_;                                    \
    wr[S][3] = *(const f32x4*)(s1_ + 4 * DD);                         \
  } while (0)

#define LOADA(T, S)                                                   \
  do {                                                                \
    _Pragma("unroll")                                                 \
    for (int mf = 0; mf < 4; ++mf)                                    \
      ar[S][mf] = *(const short8*)(Ab + (size_t)(T) * 8192 + mf * 16 * 32); \
  } while (0)

#define STAGE(S, BUF)                                                 \
  do {                                                                \
    unsigned la, ha, lb, hb;                                          \
    qtrans(wr[S][0], p, la, ha);                                      \
    qtrans(wr[S][1], p, lb, hb);                                      \
    u32x4 v0 = {la, ha, lb, hb};                                      \
    *(u32x4*)(smem + (BUF) * 16384 + kg0 * 4096 + (ns0 * 64 + nw) * 16) = v0; \
    qtrans(wr[S][2], p, la, ha);                                      \
    qtrans(wr[S][3], p, lb, hb);                                      \
    u32x4 v1 = {la, ha, lb, hb};                                      \
    *(u32x4*)(smem + (BUF) * 16384 + kg1 * 4096 + (ns1 * 64 + nw) * 16) = v1; \
  } while (0)

  // prologue
  LOADW(0, 0);
  LOADW(1, 1);
  LOADA(0, 0);
  STAGE(0, 0);
  __syncthreads();

#pragma unroll
  for (int it = 0; it < NT; ++it) {
    if (it + 1 < NT) LOADA(it + 1, (it + 1) & 1);
    if (it + 1 < NT) STAGE((it + 1) & 1, (it + 1) & 1);
    if (it + 2 < NT) LOADW(it + 2, it & 1);
    const unsigned char* bbase = smem + (it & 1) * 16384 + p * 4096 + (wn * 128 + l15) * 16;
#pragma unroll
    for (int nf = 0; nf < 8; ++nf) {
      short8 bf = *(const short8*)(bbase + nf * 256);
#pragma unroll
      for (int mf = 0; mf < 4; ++mf)
        acc[mf][nf] = __builtin_amdgcn_mfma_f32_16x16x32_bf16(ar[it & 1][mf], bf,
                                                              acc[mf][nf], 0, 0, 0);
    }
    __syncthreads();
  }
#undef LOADW
#undef LOADA
#undef STAGE

  // bf16 partial write: pair adjacent cols via lane shuffle, even lanes store u32
  unsigned short* pl = part + (size_t)ks * (256 * 4096);
#pragma unroll
  for (int mf = 0; mf < 4; ++mf)
#pragma unroll
    for (int nf = 0; nf < 8; ++nf) {
      f32x4 a = acc[mf][nf], o;
#pragma unroll
      for (int j = 0; j < 4; ++j) o[j] = __shfl_xor(a[j], 1);
      if ((l15 & 1) == 0) {
        const int col = n0 + wn * 128 + nf * 16 + l15;
        const int rb  = wm * 64 + mf * 16 + 4 * p;
#pragma unroll
        for (int j = 0; j < 4; ++j) {
          unsigned pk = (unsigned)f2bf(a[j]) | ((unsigned)f2bf(o[j]) << 16);
          *(unsigned*)((char*)pl + ((size_t)(rb + j) * 4096 + col) * 2) = pk;
        }
      }
    }
}

// sum 16 bf16 partials + bias, relu -> bf16 blocked h (+ fp32 out on last layer)
__global__ __launch_bounds__(256) void k_reduce(const unsigned short* __restrict__ part,
                                                const float* __restrict__ bias,
                                                unsigned short* __restrict__ hout,
                                                float* __restrict__ fout) {
  const size_t e = ((size_t)blockIdx.x * 256 + threadIdx.x) * 8;
  float s[8] = {0.f, 0.f, 0.f, 0.f, 0.f, 0.f, 0.f, 0.f};
#pragma unroll
  for (int ks = 0; ks < KSL; ++ks) {
    short8 v = *(const short8*)(part + (size_t)ks * (256 * 4096) + e);
#pragma unroll
    for (int j = 0; j < 8; ++j) s[j] += bf2f((unsigned short)v[j]);
  }
  const int m = (int)(e >> 12), n = (int)(e & (DD - 1));
#pragma unroll
  for (int j = 0; j < 8; ++j) s[j] = fmaxf(s[j] + bias[n + j], 0.f);
  short8 o;
#pragma unroll
  for (int j = 0; j < 8; ++j) o[j] = (short)f2bf(s[j]);
  *(short8*)(hout + (size_t)(n >> 5) * 8192 + m * 32 + (n & 31)) = o;
  if (fout) {
    f32x4 o0, o1;
#pragma unroll
    for (int j = 0; j < 4; ++j) { o0[j] = s[j]; o1[j] = s[4 + j]; }
    float* dst = fout + e;
    *(f32x4*)dst = o0;
    *(f32x4*)(dst + 4) = o1;
  }
}

extern "C" void kernel_launch(void* const* d_in, const int* in_sizes, int n_in,
                              void* d_out, int out_size, void* d_ws, size_t ws_size,
                              hipStream_t stream) {
  const float* x = (const float*)d_in[0];
  const float* W = (const float*)d_in[1];
  const float* b = (const float*)d_in[2];
  float* out = (float*)d_out;

  char* ws = (char*)d_ws;
  unsigned short* h0 = (unsigned short*)ws;               // 2 MB bf16 blocked
  unsigned short* h1 = (unsigned short*)(ws + (1 << 21)); // 2 MB
  unsigned short* part = (unsigned short*)(ws + (1 << 22)); // 16 x 2 MB bf16 partials

  k_tobf16<<<512, 256, 0, stream>>>(x, h0);
  unsigned short* hc = h0;
  unsigned short* hn = h1;
  for (int l = 0; l < NLAYER; ++l) {
    const bool last = (l == NLAYER - 1);
    k_gemm<<<256, 512, 0, stream>>>(hc, W + (size_t)l * DD * DD, part);
    k_reduce<<<512, 256, 0, stream>>>(part, b + (size_t)l * DD, hn,
                                      last ? out : nullptr);
    unsigned short* t = hc; hc = hn; hn = t;
  }
}